// Round 1
// 906.217 us; speedup vs baseline: 1.0982x; 1.0982x over previous
//
#include <hip/hip_runtime.h>

#define DIM 64
#define SBLK 1024  // elements per scan block (256 thr x 4)

// ---- bucket-scatter CSR fill parameters ----
#define SPAN 512            // nodes per bucket
#define NSHIFT 9            // log2(SPAN)
#define MAXNB 1024          // max buckets (nn <= 524288)
#define EPT 32              // edges per thread in pass A
#define EPB (256 * EPT)     // edges per block in pass A (8192)

typedef __attribute__((ext_vector_type(4))) _Float16 half4;

// ---------- degree counting over combined node space ----------
__global__ void deg_kernel(const int* __restrict__ rows, const int* __restrict__ cols,
                           int* __restrict__ deg, int nu, int E) {
    int e = blockIdx.x * blockDim.x + threadIdx.x;
    if (e < E) {
        atomicAdd(&deg[rows[e]], 1);
        atomicAdd(&deg[nu + cols[e]], 1);
    }
}

__global__ void dinv_kernel(const int* __restrict__ deg, float* __restrict__ dinv, int nn) {
    int i = blockIdx.x * blockDim.x + threadIdx.x;
    if (i < nn) dinv[i] = 1.0f / sqrtf(1e-7f + (float)deg[i]);
}

// ---------- 3-kernel exclusive scan of deg -> row_ptr ----------
__global__ void scan_partial(const int* __restrict__ deg, int* __restrict__ bsum, int nn) {
    __shared__ int lds[256];
    int t = threadIdx.x;
    int base = blockIdx.x * SBLK + t * 4;
    int s = 0;
#pragma unroll
    for (int k = 0; k < 4; k++) { int i = base + k; if (i < nn) s += deg[i]; }
    lds[t] = s; __syncthreads();
    for (int off = 128; off >= 1; off >>= 1) {
        if (t < off) lds[t] += lds[t + off];
        __syncthreads();
    }
    if (t == 0) bsum[blockIdx.x] = lds[0];
}

__global__ void scan_sums(int* __restrict__ bsum, int nblocks, int* __restrict__ total) {
    __shared__ int lds[1024];
    int t = threadIdx.x;
    int v = (t < nblocks) ? bsum[t] : 0;
    lds[t] = v; __syncthreads();
    for (int off = 1; off < 1024; off <<= 1) {
        int add = (t >= off) ? lds[t - off] : 0;
        __syncthreads();
        lds[t] += add;
        __syncthreads();
    }
    if (t < nblocks) bsum[t] = lds[t] - v;
    if (t == nblocks - 1) *total = lds[t];
}

__global__ void scan_write(const int* __restrict__ deg, const int* __restrict__ bsum,
                           int* __restrict__ row_ptr, int nn) {
    __shared__ int lds[256];
    int t = threadIdx.x;
    int base = blockIdx.x * SBLK + t * 4;
    int d[4]; int s = 0;
#pragma unroll
    for (int k = 0; k < 4; k++) { int i = base + k; d[k] = (i < nn) ? deg[i] : 0; s += d[k]; }
    lds[t] = s; __syncthreads();
    for (int off = 1; off < 256; off <<= 1) {
        int add = (t >= off) ? lds[t - off] : 0;
        __syncthreads();
        lds[t] += add;
        __syncthreads();
    }
    int run = lds[t] - s + bsum[blockIdx.x];
#pragma unroll
    for (int k = 0; k < 4; k++) {
        int i = base + k;
        if (i < nn) row_ptr[i] = run;
        run += d[k];
    }
}

// ---------- CSR fill, pass A: bucket the directed edge records ----------
// Record layout: (dst & 511) | (src << 9).  src < 2^19, so fits 28 bits.
// Records for bucket b go into rec[row_ptr[b*SPAN] .. row_ptr[(b+1)*SPAN]),
// i.e. the record buffer shares colidx's offset space -> no extra scan.
// Per-block LDS histogram => ~1 padded global atomic per bucket per block,
// and chunk-wise appends (~112 B per bucket per block) instead of 4-B
// random scatter across XCDs.
__global__ void bucket_scatter(const int* __restrict__ rows, const int* __restrict__ cols,
                               const int* __restrict__ row_ptr, int* __restrict__ bucket_cnt,
                               int* __restrict__ rec, int nu, int nn, int nb, int E) {
    __shared__ int hist[MAXNB];
    __shared__ int base[MAXNB];
    int t = threadIdx.x;
    for (int b = t; b < MAXNB; b += 256) hist[b] = 0;
    __syncthreads();
    int e0 = blockIdx.x * EPB;
    int e1 = min(e0 + EPB, E);
    // phase 1: LDS histogram of this block's records by bucket
    for (int e = e0 + t; e < e1; e += 256) {
        int r = rows[e];
        int c = nu + cols[e];
        atomicAdd(&hist[r >> NSHIFT], 1);
        atomicAdd(&hist[c >> NSHIFT], 1);
    }
    __syncthreads();
    // phase 2: reserve a chunk in each touched bucket (64B-padded counters)
    for (int b = t; b < nb; b += 256) {
        int h = hist[b];
        int off = 0;
        if (h) off = atomicAdd(&bucket_cnt[b * 16], h);
        base[b] = row_ptr[min(b << NSHIFT, nn)] + off;
        hist[b] = 0;  // reuse as within-chunk running offset
    }
    __syncthreads();
    // phase 3: place records (edges re-read; hot in L2)
    for (int e = e0 + t; e < e1; e += 256) {
        int r = rows[e];
        int c = nu + cols[e];
        int b1 = r >> NSHIFT;
        int p1 = atomicAdd(&hist[b1], 1);
        rec[base[b1] + p1] = (r & (SPAN - 1)) | (c << NSHIFT);
        int b2 = c >> NSHIFT;
        int p2 = atomicAdd(&hist[b2], 1);
        rec[base[b2] + p2] = (c & (SPAN - 1)) | (r << NSHIFT);
    }
}

// ---------- CSR fill, pass B: scatter within bucket ----------
// One block per bucket: the bucket's colidx span (~27 KB avg) is written by
// exactly one block on one XCD, so L2 lines are fully assembled and written
// back once.  row_ptr slice + per-node counters live in LDS.
__global__ void bucket_fill(const int* __restrict__ row_ptr, const int* __restrict__ rec,
                            int* __restrict__ colidx, int nn) {
    __shared__ int rp[SPAN + 1];
    __shared__ int cnt[SPAN];
    int t = threadIdx.x;
    int node0 = blockIdx.x << NSHIFT;
    for (int i = t; i <= SPAN; i += 256) {
        rp[i] = row_ptr[min(node0 + i, nn)];
        if (i < SPAN) cnt[i] = 0;
    }
    __syncthreads();
    int r0 = rp[0];
    int r1 = rp[SPAN];
    for (int i = r0 + t; i < r1; i += 256) {
        int v = rec[i];
        int dl = v & (SPAN - 1);
        int src = v >> NSHIFT;            // v >= 0, arithmetic shift ok
        int pos = rp[dl] + atomicAdd(&cnt[dl], 1);
        colidx[pos] = src;
    }
}

// ---------- pre-scale: x' = dinv ⊙ ego, stored fp16 ----------
__global__ void prescale_kernel(const float4* __restrict__ ue, const float4* __restrict__ ie,
                                const float* __restrict__ dinv, half4* __restrict__ xp,
                                int nu, int nn) {
    size_t i = (size_t)blockIdx.x * blockDim.x + threadIdx.x;
    if (i >= (size_t)nn * 16) return;
    int node = (int)(i >> 4);
    float4 v = (node < nu) ? ue[i] : ie[i - (size_t)nu * 16];
    float d = dinv[node];
    half4 h;
    h.x = (_Float16)(v.x * d); h.y = (_Float16)(v.y * d);
    h.z = (_Float16)(v.z * d); h.w = (_Float16)(v.w * d);
    xp[i] = h;
}

// ---------- fused gather-SpMM + cosine reweight + acc ----------
// one wave per node; 4 sub-groups of 16 lanes handle 4 consecutive edges;
// each lane loads half4 (8 B). xp is pre-scaled fp16 (dinv ⊙ x).
__global__ void spmm_fused(const int* __restrict__ row_ptr, const int* __restrict__ colidx,
                           const float* __restrict__ dinv,
                           const half4* __restrict__ xp,
                           const float4* __restrict__ eu, const float4* __restrict__ ei,
                           float* __restrict__ ego_norm,
                           half4* __restrict__ xn, float4* __restrict__ acc,
                           int nu, int nn, int first, int last) {
    int node = (blockIdx.x * blockDim.x + threadIdx.x) >> 6;
    int lane = threadIdx.x & 63;
    int sub  = lane >> 4;        // edge slot within step
    int li   = lane & 15;        // half4 index within row
    if (node >= nn) return;
    int start = row_ptr[node];
    int deg   = row_ptr[node + 1] - start;

    float ax = 0.f, ay = 0.f, az = 0.f, aw = 0.f;
    int j = 0;
    // full 8-edge steps: no predication, 2 gathers per lane in flight
    for (; j + 8 <= deg; j += 8) {
        int s0 = colidx[start + j + sub];
        int s1 = colidx[start + j + 4 + sub];
        half4 h0 = xp[(size_t)s0 * 16 + li];
        half4 h1 = xp[(size_t)s1 * 16 + li];
        ax += (float)h0.x + (float)h1.x;
        ay += (float)h0.y + (float)h1.y;
        az += (float)h0.z + (float)h1.z;
        aw += (float)h0.w + (float)h1.w;
    }
    // single predicated 8-wide tail
    if (j < deg) {
        int j0 = j + sub, j1 = j + 4 + sub;
        int s0 = colidx[j0 < deg ? start + j0 : start];
        int s1 = colidx[j1 < deg ? start + j1 : start];
        if (j0 < deg) {
            half4 h = xp[(size_t)s0 * 16 + li];
            ax += (float)h.x; ay += (float)h.y; az += (float)h.z; aw += (float)h.w;
        }
        if (j1 < deg) {
            half4 h = xp[(size_t)s1 * 16 + li];
            ax += (float)h.x; ay += (float)h.y; az += (float)h.z; aw += (float)h.w;
        }
    }
    // merge partial sums across the 4 sub-groups
#pragma unroll
    for (int m = 32; m >= 16; m >>= 1) {
        ax += __shfl_xor(ax, m, 64);
        ay += __shfl_xor(ay, m, 64);
        az += __shfl_xor(az, m, 64);
        aw += __shfl_xor(aw, m, 64);
    }
    float dn = dinv[node];
    ax *= dn; ay *= dn; az *= dn; aw *= dn;

    size_t o = (size_t)node * 16 + li;
    float4 ev = (node < nu) ? eu[o] : ei[o - (size_t)nu * 16];
    float dp = ax * ev.x + ay * ev.y + az * ev.z + aw * ev.w;
    float np = ax * ax + ay * ay + az * az + aw * aw;
    float ep = ev.x * ev.x + ev.y * ev.y + ev.z * ev.z + ev.w * ev.w;
#pragma unroll
    for (int m = 8; m >= 1; m >>= 1) {
        dp += __shfl_xor(dp, m, 64);
        np += __shfl_xor(np, m, 64);
        ep += __shfl_xor(ep, m, 64);
    }
    float en;
    if (first) {
        en = fmaxf(sqrtf(ep), 1e-8f);
        if (lane == 0) ego_norm[node] = en;
    } else {
        en = ego_norm[node];
    }
    float w = dp / (fmaxf(sqrtf(np), 1e-8f) * en);
    float yx = w * ax, yy = w * ay, yz = w * az, yw = w * aw;
    if (sub == 0) {
        if (!last) {
            half4 h;
            h.x = (_Float16)(yx * dn); h.y = (_Float16)(yy * dn);
            h.z = (_Float16)(yz * dn); h.w = (_Float16)(yw * dn);
            xn[o] = h;
        }
        if (first) {
            acc[o] = make_float4(yx, yy, yz, yw);
        } else {
            float4 t = acc[o];
            acc[o] = make_float4(t.x + yx, t.y + yy, t.z + yz, t.w + yw);
        }
    }
}

extern "C" void kernel_launch(void* const* d_in, const int* in_sizes, int n_in,
                              void* d_out, int out_size, void* d_ws, size_t ws_size,
                              hipStream_t stream) {
    const float* uemb = (const float*)d_in[0];
    const float* iemb = (const float*)d_in[1];
    const int*   rows = (const int*)d_in[2];
    const int*   cols = (const int*)d_in[3];
    // d_in[4] = n_layers; fixed at 3 (identical work per call required)

    const int nu = in_sizes[0] / DIM;
    const int ni = in_sizes[1] / DIM;
    const int E  = in_sizes[2];
    const int nn = nu + ni;
    const int nb = (nn + SPAN - 1) >> NSHIFT;   // buckets (<= MAXNB for nn <= 524288)

    // ---- workspace layout ----
    char* ws = (char*)d_ws;
    half4* x1       = (half4*)ws;                            // nn*16 half4 (128 B/node)
    half4* x2       = x1 + (size_t)nn * 16;                  // nn*16 half4
    int*   colidx   = (int*)(x2 + (size_t)nn * 16);          // 2E int
    int*   row_ptr  = colidx + (size_t)2 * E;                // nn+1 int
    int*   deg      = row_ptr + (nn + 1);                    // nn int
    int*   bkt_cnt  = deg + nn;                              // MAXNB*16 int (64B-padded)
    float* dinv     = (float*)(bkt_cnt + MAXNB * 16);        // nn f32
    float* ego_norm = dinv + nn;                             // nn f32
    int*   bsum     = (int*)(ego_norm + nn);                 // <=1024 int
    int*   rec      = (int*)x2;                              // 2E int, aliases x2 (dead until spmm#1)

    // ---- build normalized CSR ----
    hipMemsetAsync(deg, 0, ((size_t)nn + MAXNB * 16) * sizeof(int), stream);  // deg + bkt_cnt
    deg_kernel<<<(E + 255) / 256, 256, 0, stream>>>(rows, cols, deg, nu, E);
    dinv_kernel<<<(nn + 255) / 256, 256, 0, stream>>>(deg, dinv, nn);

    int nbs = (nn + SBLK - 1) / SBLK;
    scan_partial<<<nbs, 256, 0, stream>>>(deg, bsum, nn);
    scan_sums<<<1, 1024, 0, stream>>>(bsum, nbs, row_ptr + nn);
    scan_write<<<nbs, 256, 0, stream>>>(deg, bsum, row_ptr, nn);

    // two-level bucketed fill (replaces 4M-random-scatter fill_kernel)
    bucket_scatter<<<(E + EPB - 1) / EPB, 256, 0, stream>>>(rows, cols, row_ptr, bkt_cnt,
                                                            rec, nu, nn, nb, E);
    bucket_fill<<<nb, 256, 0, stream>>>(row_ptr, rec, colidx, nn);

    // ---- prescale layer-0 input (fp32 ego -> fp16 x') ----
    {
        size_t thr = (size_t)nn * 16;
        prescale_kernel<<<(unsigned)((thr + 255) / 256), 256, 0, stream>>>(
            (const float4*)uemb, (const float4*)iemb, dinv, x1, nu, nn);
    }

    // ---- 3 fused SpMM+reweight layers (one node per wave) ----
    unsigned gs = (unsigned)(((size_t)nn * 64 + 255) / 256);
    float4* out = (float4*)d_out;
    spmm_fused<<<gs, 256, 0, stream>>>(row_ptr, colidx, dinv, x1,
                                       (const float4*)uemb, (const float4*)iemb, ego_norm,
                                       x2, out, nu, nn, 1, 0);
    spmm_fused<<<gs, 256, 0, stream>>>(row_ptr, colidx, dinv, x2,
                                       (const float4*)uemb, (const float4*)iemb, ego_norm,
                                       x1, out, nu, nn, 0, 0);
    spmm_fused<<<gs, 256, 0, stream>>>(row_ptr, colidx, dinv, x1,
                                       (const float4*)uemb, (const float4*)iemb, ego_norm,
                                       x2, out, nu, nn, 0, 1);
}

// Round 2
// 718.998 us; speedup vs baseline: 1.3842x; 1.2604x over previous
//
#include <hip/hip_runtime.h>

#define DIM 64

// ---- bucket-scatter CSR build parameters ----
#define SPAN 512            // nodes per bucket
#define NSHIFT 9            // log2(SPAN)
#define MAXNB 1024          // max buckets (nn <= 524288)
#define BCAP 12288          // records per bucket region (mean ~10240 + 20 sigma)
#define EPT 32              // edges per thread in pass A
#define EPB (256 * EPT)     // edges per block in pass A (8192)

typedef __attribute__((ext_vector_type(4))) _Float16 half4;

// ---------- CSR build, pass A: bucket the directed edge records ----------
// Record layout: (dst & 511) | (src << 9).  src < 2^19, so fits 28 bits.
// Records for bucket b go into rec[b*BCAP ..), counted in bucket_cnt[b*16]
// (64B-padded counters).  Per-block LDS histogram => ~1 global atomic per
// bucket per block + chunk-wise appends; no row_ptr needed yet.
__global__ void bucket_scatter2(const int* __restrict__ rows, const int* __restrict__ cols,
                                int* __restrict__ bucket_cnt, int* __restrict__ rec,
                                int nu, int nb, int E) {
    __shared__ int hist[MAXNB];
    __shared__ int base[MAXNB];
    int t = threadIdx.x;
    for (int b = t; b < MAXNB; b += 256) hist[b] = 0;
    __syncthreads();
    int e0 = blockIdx.x * EPB;
    int e1 = min(e0 + EPB, E);
    // phase 1: LDS histogram of this block's records by bucket
    for (int e = e0 + t; e < e1; e += 256) {
        int r = rows[e];
        int c = nu + cols[e];
        atomicAdd(&hist[r >> NSHIFT], 1);
        atomicAdd(&hist[c >> NSHIFT], 1);
    }
    __syncthreads();
    // phase 2: reserve a chunk in each touched bucket
    for (int b = t; b < nb; b += 256) {
        int h = hist[b];
        int off = 0;
        if (h) off = atomicAdd(&bucket_cnt[b * 16], h);
        if (off > BCAP) off = BCAP;  // memory-safety clamp (statistically unreachable)
        base[b] = b * BCAP + off;
        hist[b] = 0;  // reuse as within-chunk running offset
    }
    __syncthreads();
    // phase 3: place records (edges re-read; hot in cache)
    for (int e = e0 + t; e < e1; e += 256) {
        int r = rows[e];
        int c = nu + cols[e];
        int b1 = r >> NSHIFT;
        int p1 = atomicAdd(&hist[b1], 1);
        rec[base[b1] + p1] = (r & (SPAN - 1)) | (c << NSHIFT);
        int b2 = c >> NSHIFT;
        int p2 = atomicAdd(&hist[b2], 1);
        rec[base[b2] + p2] = (c & (SPAN - 1)) | (r << NSHIFT);
    }
}

// ---------- CSR build, pass B: scan bucket sizes -> global bases ----------
__global__ void bucket_scan(const int* __restrict__ bucket_cnt, int* __restrict__ bucket_base,
                            int* __restrict__ row_ptr_end, int nb) {
    __shared__ int lds[1024];
    int t = threadIdx.x;
    int v = (t < nb) ? bucket_cnt[t * 16] : 0;
    lds[t] = v; __syncthreads();
    for (int off = 1; off < 1024; off <<= 1) {
        int add = (t >= off) ? lds[t - off] : 0;
        __syncthreads();
        lds[t] += add;
        __syncthreads();
    }
    if (t < nb) bucket_base[t] = lds[t] - v;   // exclusive prefix
    if (t == nb - 1) *row_ptr_end = lds[t];    // row_ptr[nn] = 2E
}

// ---------- CSR build, pass C: per-bucket deg count + scan + fill ----------
// One block per bucket.  Degree histogram and node-level prefix scan happen
// entirely in LDS, producing row_ptr AND dinv for the bucket's 512 nodes;
// then records scatter into the bucket's colidx span (one XCD assembles each
// L2 line).  Replaces deg_kernel + dinv_kernel + 3-kernel node scan.
__global__ void bucket_fill2(const int* __restrict__ bucket_cnt, const int* __restrict__ bucket_base,
                             const int* __restrict__ rec, int* __restrict__ colidx,
                             int* __restrict__ row_ptr, float* __restrict__ dinv, int nn) {
    __shared__ int cnt[SPAN];
    __shared__ int pfx[SPAN];
    __shared__ int s256[256];
    int t = threadIdx.x;
    int b = blockIdx.x;
    int node0 = b << NSHIFT;
    int nrec = bucket_cnt[b * 16];
    const int* r0 = rec + (size_t)b * BCAP;
    int gbase = bucket_base[b];

    for (int i = t; i < SPAN; i += 256) cnt[i] = 0;
    __syncthreads();
    // degree histogram over this bucket's records
    for (int i = t; i < nrec; i += 256)
        atomicAdd(&cnt[r0[i] & (SPAN - 1)], 1);
    __syncthreads();
    // 512-wide exclusive scan with 256 threads (2 elements each)
    int d0 = cnt[2 * t], d1 = cnt[2 * t + 1];
    int s = d0 + d1;
    s256[t] = s; __syncthreads();
    for (int off = 1; off < 256; off <<= 1) {
        int add = (t >= off) ? s256[t - off] : 0;
        __syncthreads();
        s256[t] += add;
        __syncthreads();
    }
    int excl = s256[t] - s;
    pfx[2 * t]     = excl;
    pfx[2 * t + 1] = excl + d0;
    int n0 = node0 + 2 * t, n1 = n0 + 1;
    if (n0 < nn) { row_ptr[n0] = gbase + excl;      dinv[n0] = rsqrtf(1e-7f + (float)d0); }
    if (n1 < nn) { row_ptr[n1] = gbase + excl + d0; dinv[n1] = rsqrtf(1e-7f + (float)d1); }
    // reset cnt for placement pass
    cnt[2 * t] = 0; cnt[2 * t + 1] = 0;
    __syncthreads();
    // place records
    for (int i = t; i < nrec; i += 256) {
        int v = r0[i];
        int dl = v & (SPAN - 1);
        int src = v >> NSHIFT;
        int pos = gbase + pfx[dl] + atomicAdd(&cnt[dl], 1);
        colidx[pos] = src;
    }
}

// ---------- pre-scale: x' = dinv ⊙ ego, stored fp16 ----------
__global__ void prescale_kernel(const float4* __restrict__ ue, const float4* __restrict__ ie,
                                const float* __restrict__ dinv, half4* __restrict__ xp,
                                int nu, int nn) {
    size_t i = (size_t)blockIdx.x * blockDim.x + threadIdx.x;
    if (i >= (size_t)nn * 16) return;
    int node = (int)(i >> 4);
    float4 v = (node < nu) ? ue[i] : ie[i - (size_t)nu * 16];
    float d = dinv[node];
    half4 h;
    h.x = (_Float16)(v.x * d); h.y = (_Float16)(v.y * d);
    h.z = (_Float16)(v.z * d); h.w = (_Float16)(v.w * d);
    xp[i] = h;
}

// ---------- fused gather-SpMM + cosine reweight + acc ----------
// one wave per node; 4 sub-groups of 16 lanes handle 4 consecutive edges;
// each lane loads half4 (8 B). xp is pre-scaled fp16 (dinv ⊙ x).
__global__ void spmm_fused(const int* __restrict__ row_ptr, const int* __restrict__ colidx,
                           const float* __restrict__ dinv,
                           const half4* __restrict__ xp,
                           const float4* __restrict__ eu, const float4* __restrict__ ei,
                           float* __restrict__ ego_norm,
                           half4* __restrict__ xn, float4* __restrict__ acc,
                           int nu, int nn, int first, int last) {
    int node = (blockIdx.x * blockDim.x + threadIdx.x) >> 6;
    int lane = threadIdx.x & 63;
    int sub  = lane >> 4;        // edge slot within step
    int li   = lane & 15;        // half4 index within row
    if (node >= nn) return;
    int start = row_ptr[node];
    int deg   = row_ptr[node + 1] - start;

    float ax = 0.f, ay = 0.f, az = 0.f, aw = 0.f;
    int j = 0;
    // full 8-edge steps: no predication, 2 gathers per lane in flight
    for (; j + 8 <= deg; j += 8) {
        int s0 = colidx[start + j + sub];
        int s1 = colidx[start + j + 4 + sub];
        half4 h0 = xp[(size_t)s0 * 16 + li];
        half4 h1 = xp[(size_t)s1 * 16 + li];
        ax += (float)h0.x + (float)h1.x;
        ay += (float)h0.y + (float)h1.y;
        az += (float)h0.z + (float)h1.z;
        aw += (float)h0.w + (float)h1.w;
    }
    // single predicated 8-wide tail
    if (j < deg) {
        int j0 = j + sub, j1 = j + 4 + sub;
        int s0 = colidx[j0 < deg ? start + j0 : start];
        int s1 = colidx[j1 < deg ? start + j1 : start];
        if (j0 < deg) {
            half4 h = xp[(size_t)s0 * 16 + li];
            ax += (float)h.x; ay += (float)h.y; az += (float)h.z; aw += (float)h.w;
        }
        if (j1 < deg) {
            half4 h = xp[(size_t)s1 * 16 + li];
            ax += (float)h.x; ay += (float)h.y; az += (float)h.z; aw += (float)h.w;
        }
    }
    // merge partial sums across the 4 sub-groups
#pragma unroll
    for (int m = 32; m >= 16; m >>= 1) {
        ax += __shfl_xor(ax, m, 64);
        ay += __shfl_xor(ay, m, 64);
        az += __shfl_xor(az, m, 64);
        aw += __shfl_xor(aw, m, 64);
    }
    float dn = dinv[node];
    ax *= dn; ay *= dn; az *= dn; aw *= dn;

    size_t o = (size_t)node * 16 + li;
    float4 ev = (node < nu) ? eu[o] : ei[o - (size_t)nu * 16];
    float dp = ax * ev.x + ay * ev.y + az * ev.z + aw * ev.w;
    float np = ax * ax + ay * ay + az * az + aw * aw;
    float ep = ev.x * ev.x + ev.y * ev.y + ev.z * ev.z + ev.w * ev.w;
#pragma unroll
    for (int m = 8; m >= 1; m >>= 1) {
        dp += __shfl_xor(dp, m, 64);
        np += __shfl_xor(np, m, 64);
        ep += __shfl_xor(ep, m, 64);
    }
    float en;
    if (first) {
        en = fmaxf(sqrtf(ep), 1e-8f);
        if (lane == 0) ego_norm[node] = en;
    } else {
        en = ego_norm[node];
    }
    float w = dp / (fmaxf(sqrtf(np), 1e-8f) * en);
    float yx = w * ax, yy = w * ay, yz = w * az, yw = w * aw;
    if (sub == 0) {
        if (!last) {
            half4 h;
            h.x = (_Float16)(yx * dn); h.y = (_Float16)(yy * dn);
            h.z = (_Float16)(yz * dn); h.w = (_Float16)(yw * dn);
            xn[o] = h;
        }
        if (first) {
            acc[o] = make_float4(yx, yy, yz, yw);
        } else {
            float4 t = acc[o];
            acc[o] = make_float4(t.x + yx, t.y + yy, t.z + yz, t.w + yw);
        }
    }
}

extern "C" void kernel_launch(void* const* d_in, const int* in_sizes, int n_in,
                              void* d_out, int out_size, void* d_ws, size_t ws_size,
                              hipStream_t stream) {
    const float* uemb = (const float*)d_in[0];
    const float* iemb = (const float*)d_in[1];
    const int*   rows = (const int*)d_in[2];
    const int*   cols = (const int*)d_in[3];
    // d_in[4] = n_layers; fixed at 3 (identical work per call required)

    const int nu = in_sizes[0] / DIM;
    const int ni = in_sizes[1] / DIM;
    const int E  = in_sizes[2];
    const int nn = nu + ni;
    const int nb = (nn + SPAN - 1) >> NSHIFT;   // buckets (<= MAXNB for nn <= 524288)

    // ---- workspace layout ----
    char* ws = (char*)d_ws;
    half4* x1       = (half4*)ws;                            // nn*16 half4 (128 B/node)
    half4* x2       = x1 + (size_t)nn * 16;                  // nn*16 half4
    int*   colidx   = (int*)(x2 + (size_t)nn * 16);          // 2E int
    int*   row_ptr  = colidx + (size_t)2 * E;                // nn+1 int
    int*   bkt_cnt  = row_ptr + (nn + 1);                    // MAXNB*16 int (64B-padded)
    int*   bkt_base = bkt_cnt + MAXNB * 16;                  // MAXNB int
    float* dinv     = (float*)(bkt_base + MAXNB);            // nn f32
    float* ego_norm = dinv + nn;                             // nn f32
    int*   rec      = (int*)x2;                              // nb*BCAP int, aliases x2
                                                             // (dead until spmm #1; nb*BCAP*4B <= nn*128B)

    // ---- build normalized CSR: 3 kernels, zero random global atomics ----
    hipMemsetAsync(bkt_cnt, 0, (size_t)MAXNB * 16 * sizeof(int), stream);
    bucket_scatter2<<<(E + EPB - 1) / EPB, 256, 0, stream>>>(rows, cols, bkt_cnt, rec, nu, nb, E);
    bucket_scan<<<1, 1024, 0, stream>>>(bkt_cnt, bkt_base, row_ptr + nn, nb);
    bucket_fill2<<<nb, 256, 0, stream>>>(bkt_cnt, bkt_base, rec, colidx, row_ptr, dinv, nn);

    // ---- prescale layer-0 input (fp32 ego -> fp16 x') ----
    {
        size_t thr = (size_t)nn * 16;
        prescale_kernel<<<(unsigned)((thr + 255) / 256), 256, 0, stream>>>(
            (const float4*)uemb, (const float4*)iemb, dinv, x1, nu, nn);
    }

    // ---- 3 fused SpMM+reweight layers (one node per wave) ----
    unsigned gs = (unsigned)(((size_t)nn * 64 + 255) / 256);
    float4* out = (float4*)d_out;
    spmm_fused<<<gs, 256, 0, stream>>>(row_ptr, colidx, dinv, x1,
                                       (const float4*)uemb, (const float4*)iemb, ego_norm,
                                       x2, out, nu, nn, 1, 0);
    spmm_fused<<<gs, 256, 0, stream>>>(row_ptr, colidx, dinv, x2,
                                       (const float4*)uemb, (const float4*)iemb, ego_norm,
                                       x1, out, nu, nn, 0, 0);
    spmm_fused<<<gs, 256, 0, stream>>>(row_ptr, colidx, dinv, x1,
                                       (const float4*)uemb, (const float4*)iemb, ego_norm,
                                       x2, out, nu, nn, 0, 1);
}

// Round 4
// 645.342 us; speedup vs baseline: 1.5422x; 1.1141x over previous
//
#include <hip/hip_runtime.h>

#define DIM 64

// ---- bucket-scatter CSR build parameters ----
#define SPAN 512            // nodes per bucket
#define NSHIFT 9            // log2(SPAN)
#define MAXNB 1024          // max buckets (nn <= 524288)
#define BCAP 12288          // records per bucket region (mean ~10240 + 20 sigma)
#define EPT 32              // edges per thread in pass A
#define EPB (256 * EPT)     // edges per block in pass A (8192)

typedef __attribute__((ext_vector_type(4))) _Float16 half4;
typedef __attribute__((ext_vector_type(2))) int int2v;

// ---------- CSR build, pass A: bucket the directed edge records ----------
__global__ void bucket_scatter2(const int* __restrict__ rows, const int* __restrict__ cols,
                                int* __restrict__ bucket_cnt, int* __restrict__ rec,
                                int nu, int nb, int E) {
    __shared__ int hist[MAXNB];
    __shared__ int base[MAXNB];
    int t = threadIdx.x;
    for (int b = t; b < MAXNB; b += 256) hist[b] = 0;
    __syncthreads();
    int e0 = blockIdx.x * EPB;
    int e1 = min(e0 + EPB, E);
    for (int e = e0 + t; e < e1; e += 256) {
        int r = rows[e];
        int c = nu + cols[e];
        atomicAdd(&hist[r >> NSHIFT], 1);
        atomicAdd(&hist[c >> NSHIFT], 1);
    }
    __syncthreads();
    for (int b = t; b < nb; b += 256) {
        int h = hist[b];
        int off = 0;
        if (h) off = atomicAdd(&bucket_cnt[b * 16], h);
        if (off > BCAP) off = BCAP;  // memory-safety clamp (statistically unreachable)
        base[b] = b * BCAP + off;
        hist[b] = 0;  // reuse as within-chunk running offset
    }
    __syncthreads();
    for (int e = e0 + t; e < e1; e += 256) {
        int r = rows[e];
        int c = nu + cols[e];
        int b1 = r >> NSHIFT;
        int p1 = atomicAdd(&hist[b1], 1);
        rec[base[b1] + p1] = (r & (SPAN - 1)) | (c << NSHIFT);
        int b2 = c >> NSHIFT;
        int p2 = atomicAdd(&hist[b2], 1);
        rec[base[b2] + p2] = (c & (SPAN - 1)) | (r << NSHIFT);
    }
}

// ---------- CSR build, pass B: scan bucket sizes -> global bases ----------
__global__ void bucket_scan(const int* __restrict__ bucket_cnt, int* __restrict__ bucket_base,
                            int* __restrict__ row_ptr_end, int nb) {
    __shared__ int lds[1024];
    int t = threadIdx.x;
    int v = (t < nb) ? bucket_cnt[t * 16] : 0;
    lds[t] = v; __syncthreads();
    for (int off = 1; off < 1024; off <<= 1) {
        int add = (t >= off) ? lds[t - off] : 0;
        __syncthreads();
        lds[t] += add;
        __syncthreads();
    }
    if (t < nb) bucket_base[t] = lds[t] - v;   // exclusive prefix
    if (t == nb - 1) *row_ptr_end = lds[t];    // row_ptr[nn] = 2E
}

// ---------- CSR build, pass C: per-bucket deg count + scan + fill + prescale ----------
// One block per bucket.  Degree histogram + node prefix scan in LDS produce
// row_ptr; records scatter into the bucket's colidx span.  After placement,
// cnt[] holds the degrees again, so the fused prescale epilogue computes
// dinv on the fly and writes x0 = dinv ⊙ ego (fp16) for its 512 nodes.
__global__ void bucket_fill2(const int* __restrict__ bucket_cnt, const int* __restrict__ bucket_base,
                             const int* __restrict__ rec, int* __restrict__ colidx,
                             int* __restrict__ row_ptr,
                             const float4* __restrict__ ue, const float4* __restrict__ ie,
                             half4* __restrict__ x0, int nu, int nn) {
    __shared__ int cnt[SPAN];
    __shared__ int pfx[SPAN];
    __shared__ int s256[256];
    int t = threadIdx.x;
    int b = blockIdx.x;
    int node0 = b << NSHIFT;
    int nrec = bucket_cnt[b * 16];
    const int* r0 = rec + (size_t)b * BCAP;
    int gbase = bucket_base[b];

    for (int i = t; i < SPAN; i += 256) cnt[i] = 0;
    __syncthreads();
    for (int i = t; i < nrec; i += 256)
        atomicAdd(&cnt[r0[i] & (SPAN - 1)], 1);
    __syncthreads();
    // 512-wide exclusive scan with 256 threads (2 elements each)
    int d0 = cnt[2 * t], d1 = cnt[2 * t + 1];
    int s = d0 + d1;
    s256[t] = s; __syncthreads();
    for (int off = 1; off < 256; off <<= 1) {
        int add = (t >= off) ? s256[t - off] : 0;
        __syncthreads();
        s256[t] += add;
        __syncthreads();
    }
    int excl = s256[t] - s;
    pfx[2 * t]     = excl;
    pfx[2 * t + 1] = excl + d0;
    int n0 = node0 + 2 * t, n1 = n0 + 1;
    if (n0 < nn) row_ptr[n0] = gbase + excl;
    if (n1 < nn) row_ptr[n1] = gbase + excl + d0;
    cnt[2 * t] = 0; cnt[2 * t + 1] = 0;
    __syncthreads();
    // place records
    for (int i = t; i < nrec; i += 256) {
        int v = r0[i];
        int dl = v & (SPAN - 1);
        int src = v >> NSHIFT;
        int pos = gbase + pfx[dl] + atomicAdd(&cnt[dl], 1);
        colidx[pos] = src;
    }
    __syncthreads();
    // fused prescale: cnt[] == degree again; x0 = dinv ⊙ ego (fp16)
    for (int i = t; i < SPAN * 16; i += 256) {
        int nl = i >> 4;
        int node = node0 + nl;
        if (node >= nn) break;    // node monotone in i -> safe
        int li = i & 15;
        float d = rsqrtf(1e-7f + (float)cnt[nl]);
        size_t o = (size_t)node * 16 + li;
        float4 v = (node < nu) ? ue[o] : ie[o - (size_t)nu * 16];
        half4 h;
        h.x = (_Float16)(v.x * d); h.y = (_Float16)(v.y * d);
        h.z = (_Float16)(v.z * d); h.w = (_Float16)(v.w * d);
        x0[o] = h;
    }
}

// ---------- fused gather-SpMM + cosine reweight + acc ----------
// one wave per node; 4 sub-groups of 16 lanes handle 4 consecutive edges;
// each lane loads half4 (8 B).  Accumulation in packed fp16 (v_pk_add_f16),
// converted to fp32 only after the cross-subgroup merge (two 32-bit shuffles).
// EGO16: cosine operand is the fp16 prescaled x0 row (dinv cancels):
//   w = dot(x,x0) / (max(|x|,eps) * max(|x0|, eps*dn))
// else: fp32 ego rows from the input buffers (en recomputed per layer, same value).
template<bool EGO16>
__global__ void spmm_fused(const int* __restrict__ row_ptr, const int* __restrict__ colidx,
                           const half4* __restrict__ xp, const half4* __restrict__ x0,
                           const float4* __restrict__ eu, const float4* __restrict__ ei,
                           half4* __restrict__ xn, float4* __restrict__ acc,
                           int nu, int nn, int first, int last) {
    int node = (blockIdx.x * blockDim.x + threadIdx.x) >> 6;
    int lane = threadIdx.x & 63;
    int sub  = lane >> 4;        // edge slot within step
    int li   = lane & 15;        // half4 index within row
    if (node >= nn) return;
    int start = row_ptr[node];
    int deg   = row_ptr[node + 1] - start;

    half4 hacc0 = {(_Float16)0, (_Float16)0, (_Float16)0, (_Float16)0};
    half4 hacc1 = hacc0;
    const unsigned li8 = (unsigned)li << 3;
    int j = 0;
    // full 8-edge steps: 4 independent loads in flight, 2 pk-adds
    for (; j + 8 <= deg; j += 8) {
        unsigned c0 = (unsigned)(start + j + sub) << 2;
        int s0 = *(const int*)((const char*)colidx + c0);
        int s1 = *(const int*)((const char*)colidx + c0 + 16u);
        half4 h0 = *(const half4*)((const char*)xp + (((unsigned)s0 << 7) + li8));
        half4 h1 = *(const half4*)((const char*)xp + (((unsigned)s1 << 7) + li8));
        hacc0 += h0;
        hacc1 += h1;
    }
    // single predicated 8-wide tail
    if (j < deg) {
        int j0 = j + sub, j1 = j + 4 + sub;
        unsigned c0 = (unsigned)(j0 < deg ? start + j0 : start) << 2;
        unsigned c1 = (unsigned)(j1 < deg ? start + j1 : start) << 2;
        int s0 = *(const int*)((const char*)colidx + c0);
        int s1 = *(const int*)((const char*)colidx + c1);
        if (j0 < deg) hacc0 += *(const half4*)((const char*)xp + (((unsigned)s0 << 7) + li8));
        if (j1 < deg) hacc1 += *(const half4*)((const char*)xp + (((unsigned)s1 << 7) + li8));
    }
    // merge partial sums across the 4 sub-groups (packed fp16, 2x 32-bit shuffles)
    hacc0 += hacc1;
#pragma unroll
    for (int m = 32; m >= 16; m >>= 1) {
        int2v p = __builtin_bit_cast(int2v, hacc0);
        int2v q;
        q.x = __shfl_xor(p.x, m, 64);
        q.y = __shfl_xor(p.y, m, 64);
        hacc0 += __builtin_bit_cast(half4, q);
    }
    float dn = rsqrtf(1e-7f + (float)deg);
    float ax = (float)hacc0.x * dn, ay = (float)hacc0.y * dn;
    float az = (float)hacc0.z * dn, aw = (float)hacc0.w * dn;

    size_t o = (size_t)node * 16 + li;
    float ex, ey, ez, ew;
    if constexpr (EGO16) {
        half4 e = x0[o];
        ex = (float)e.x; ey = (float)e.y; ez = (float)e.z; ew = (float)e.w;
    } else {
        float4 ev = (node < nu) ? eu[o] : ei[o - (size_t)nu * 16];
        ex = ev.x; ey = ev.y; ez = ev.z; ew = ev.w;
    }
    float dp = ax * ex + ay * ey + az * ez + aw * ew;
    float np = ax * ax + ay * ay + az * az + aw * aw;
    float ep = ex * ex + ey * ey + ez * ez + ew * ew;
#pragma unroll
    for (int m = 8; m >= 1; m >>= 1) {
        dp += __shfl_xor(dp, m, 64);
        np += __shfl_xor(np, m, 64);
        ep += __shfl_xor(ep, m, 64);
    }
    float en = EGO16 ? fmaxf(sqrtf(ep), 1e-8f * dn) : fmaxf(sqrtf(ep), 1e-8f);
    float w = dp / (fmaxf(sqrtf(np), 1e-8f) * en);
    float yx = w * ax, yy = w * ay, yz = w * az, yw = w * aw;
    if (sub == 0) {
        if (!last) {
            half4 h;
            h.x = (_Float16)(yx * dn); h.y = (_Float16)(yy * dn);
            h.z = (_Float16)(yz * dn); h.w = (_Float16)(yw * dn);
            xn[o] = h;
        }
        if (first) {
            acc[o] = make_float4(yx, yy, yz, yw);
        } else {
            float4 t = acc[o];
            acc[o] = make_float4(t.x + yx, t.y + yy, t.z + yz, t.w + yw);
        }
    }
}

extern "C" void kernel_launch(void* const* d_in, const int* in_sizes, int n_in,
                              void* d_out, int out_size, void* d_ws, size_t ws_size,
                              hipStream_t stream) {
    const float* uemb = (const float*)d_in[0];
    const float* iemb = (const float*)d_in[1];
    const int*   rows = (const int*)d_in[2];
    const int*   cols = (const int*)d_in[3];
    // d_in[4] = n_layers; fixed at 3 (identical work per call required)

    const int nu = in_sizes[0] / DIM;
    const int ni = in_sizes[1] / DIM;
    const int E  = in_sizes[2];
    const int nn = nu + ni;
    const int nb = (nn + SPAN - 1) >> NSHIFT;   // buckets (<= MAXNB for nn <= 524288)

    // ---- workspace layout ----
    const size_t hbuf = (size_t)nn * 16 * sizeof(half4);     // 128 B/node
    const size_t rec_bytes = (size_t)nb * BCAP * sizeof(int);
    const size_t bufB = hbuf > rec_bytes ? hbuf : rec_bytes;
    const size_t cid_bytes = (size_t)2 * E * sizeof(int);
    const size_t rp_bytes  = (size_t)(nn + 1) * sizeof(int);
    const size_t bc_bytes  = (size_t)MAXNB * 16 * sizeof(int);
    const size_t bb_bytes  = (size_t)MAXNB * sizeof(int);
    const size_t need3 = hbuf + bufB + hbuf + cid_bytes + rp_bytes + bc_bytes + bb_bytes + 1024;
    const bool ego16 = (ws_size >= need3);   // 3-buffer fp16-ego path if ws allows

    char* ws = (char*)d_ws;
    half4* A = (half4*)ws;                       // x0 = prescaled ego (fp16)
    half4* B = (half4*)(ws + hbuf);              // xn buffer 1 (aliases rec during build)
    half4* C = nullptr;
    char* after;
    if (ego16) { C = (half4*)(ws + hbuf + bufB); after = ws + hbuf + bufB + hbuf; }
    else       { after = ws + hbuf + bufB; }
    int* colidx   = (int*)after;
    int* row_ptr  = (int*)(after + cid_bytes);
    int* bkt_cnt  = (int*)(after + cid_bytes + rp_bytes);
    int* bkt_base = (int*)(after + cid_bytes + rp_bytes + bc_bytes);
    int* rec      = (int*)B;

    // ---- build normalized CSR + prescale: 3 kernels, zero random global atomics ----
    hipMemsetAsync(bkt_cnt, 0, bc_bytes, stream);
    bucket_scatter2<<<(E + EPB - 1) / EPB, 256, 0, stream>>>(rows, cols, bkt_cnt, rec, nu, nb, E);
    bucket_scan<<<1, 1024, 0, stream>>>(bkt_cnt, bkt_base, row_ptr + nn, nb);
    bucket_fill2<<<nb, 256, 0, stream>>>(bkt_cnt, bkt_base, rec, colidx, row_ptr,
                                         (const float4*)uemb, (const float4*)iemb, A, nu, nn);

    // ---- 3 fused SpMM+reweight layers (one node per wave) ----
    unsigned gs = (unsigned)(((size_t)nn * 64 + 255) / 256);
    float4* out = (float4*)d_out;
    if (ego16) {
        spmm_fused<true><<<gs, 256, 0, stream>>>(row_ptr, colidx, A, A, nullptr, nullptr,
                                                 B, out, nu, nn, 1, 0);
        spmm_fused<true><<<gs, 256, 0, stream>>>(row_ptr, colidx, B, A, nullptr, nullptr,
                                                 C, out, nu, nn, 0, 0);
        spmm_fused<true><<<gs, 256, 0, stream>>>(row_ptr, colidx, C, A, nullptr, nullptr,
                                                 nullptr, out, nu, nn, 0, 1);
    } else {
        spmm_fused<false><<<gs, 256, 0, stream>>>(row_ptr, colidx, A, nullptr,
                                                  (const float4*)uemb, (const float4*)iemb,
                                                  B, out, nu, nn, 1, 0);
        spmm_fused<false><<<gs, 256, 0, stream>>>(row_ptr, colidx, B, nullptr,
                                                  (const float4*)uemb, (const float4*)iemb,
                                                  A, out, nu, nn, 0, 0);
        spmm_fused<false><<<gs, 256, 0, stream>>>(row_ptr, colidx, A, nullptr,
                                                  (const float4*)uemb, (const float4*)iemb,
                                                  nullptr, out, nu, nn, 0, 1);
    }
}

// Round 5
// 622.807 us; speedup vs baseline: 1.5980x; 1.0362x over previous
//
#include <hip/hip_runtime.h>

#define DIM 64

// ---- bucket-scatter CSR build parameters ----
#define SPAN 256            // nodes per bucket
#define NSHIFT 8            // log2(SPAN)
#define MAXNB 2048          // max buckets (nn <= 524288)
#define BCAP 8192           // records per bucket region (item-bucket mean ~5120 + ~42 sigma)
#define EPT 16              // edges per thread in pass A
#define EPB (256 * EPT)     // edges per block in pass A (4096)

typedef __attribute__((ext_vector_type(4))) _Float16 half4;
typedef __attribute__((ext_vector_type(8))) _Float16 half8;
typedef __attribute__((ext_vector_type(4))) int int4v;

// ---------- CSR build, pass A: bucket the directed edge records ----------
// Record: (dst & 255) | (src << 8); src < 2^19 -> fits 27 bits.
// Bucket b's records go to rec[b*BCAP ..), counted in bucket_cnt[b*16].
__global__ void bucket_scatter2(const int* __restrict__ rows, const int* __restrict__ cols,
                                int* __restrict__ bucket_cnt, int* __restrict__ rec,
                                int nu, int nb, int E) {
    __shared__ int hist[MAXNB];
    __shared__ int base[MAXNB];
    int t = threadIdx.x;
    for (int b = t; b < MAXNB; b += 256) hist[b] = 0;
    __syncthreads();
    int e0 = blockIdx.x * EPB;
    int e1 = min(e0 + EPB, E);
    for (int e = e0 + t; e < e1; e += 256) {
        int r = rows[e];
        int c = nu + cols[e];
        atomicAdd(&hist[r >> NSHIFT], 1);
        atomicAdd(&hist[c >> NSHIFT], 1);
    }
    __syncthreads();
    for (int b = t; b < nb; b += 256) {
        int h = hist[b];
        int off = 0;
        if (h) off = atomicAdd(&bucket_cnt[b * 16], h);
        if (off > BCAP) off = BCAP;  // memory-safety clamp (statistically unreachable)
        base[b] = b * BCAP + off;
        hist[b] = 0;  // reuse as within-chunk running offset
    }
    __syncthreads();
    for (int e = e0 + t; e < e1; e += 256) {
        int r = rows[e];
        int c = nu + cols[e];
        int b1 = r >> NSHIFT;
        int p1 = atomicAdd(&hist[b1], 1);
        rec[base[b1] + p1] = (r & (SPAN - 1)) | (c << NSHIFT);
        int b2 = c >> NSHIFT;
        int p2 = atomicAdd(&hist[b2], 1);
        rec[base[b2] + p2] = (c & (SPAN - 1)) | (r << NSHIFT);
    }
}

// ---------- CSR build, pass B: scan bucket sizes -> global bases ----------
// 1024 threads x 2 elements covers nb <= 2048.
__global__ void bucket_scan(const int* __restrict__ bucket_cnt, int* __restrict__ bucket_base,
                            int* __restrict__ row_ptr_end, int nb) {
    __shared__ int lds[1024];
    int t = threadIdx.x;
    int i0 = 2 * t, i1 = 2 * t + 1;
    int v0 = (i0 < nb) ? bucket_cnt[i0 * 16] : 0;
    int v1 = (i1 < nb) ? bucket_cnt[i1 * 16] : 0;
    int s = v0 + v1;
    lds[t] = s; __syncthreads();
    for (int off = 1; off < 1024; off <<= 1) {
        int add = (t >= off) ? lds[t - off] : 0;
        __syncthreads();
        lds[t] += add;
        __syncthreads();
    }
    int excl = lds[t] - s;
    if (i0 < nb) bucket_base[i0] = excl;
    if (i1 < nb) bucket_base[i1] = excl + v0;
    if (i0 == nb - 1) *row_ptr_end = excl + v0;
    if (i1 == nb - 1) *row_ptr_end = excl + v0 + v1;
}

// ---------- CSR build, pass C: per-bucket deg histogram + scan + place ----------
// One block per bucket (256 nodes = 256 threads, 1 node/thread for the scan).
__global__ void bucket_fill3(const int* __restrict__ bucket_cnt, const int* __restrict__ bucket_base,
                             const int* __restrict__ rec, int* __restrict__ colidx,
                             int* __restrict__ row_ptr, int nn) {
    __shared__ int cnt[SPAN];   // histogram, then prefix
    __shared__ int lds[256];    // scan buffer, then placement counters
    int t = threadIdx.x;
    int b = blockIdx.x;
    int node0 = b << NSHIFT;
    int nrec = bucket_cnt[b * 16];
    const int* r0 = rec + (size_t)b * BCAP;
    int gbase = bucket_base[b];

    cnt[t] = 0;
    __syncthreads();
    for (int i = t; i < nrec; i += 256)
        atomicAdd(&cnt[r0[i] & (SPAN - 1)], 1);
    __syncthreads();
    int d = cnt[t];
    lds[t] = d; __syncthreads();
    for (int off = 1; off < 256; off <<= 1) {
        int add = (t >= off) ? lds[t - off] : 0;
        __syncthreads();
        lds[t] += add;
        __syncthreads();
    }
    int excl = lds[t] - d;
    int node = node0 + t;
    if (node < nn) row_ptr[node] = gbase + excl;
    cnt[t] = excl;   // per-node start offset
    lds[t] = 0;      // placement counters
    __syncthreads();
    for (int i = t; i < nrec; i += 256) {
        int v = r0[i];
        int dl = v & (SPAN - 1);
        int pos = gbase + cnt[dl] + atomicAdd(&lds[dl], 1);
        colidx[pos] = v >> NSHIFT;
    }
}

// ---------- pre-scale: x0 = dinv ⊙ ego (fp16); deg from row_ptr deltas ----------
__global__ void prescale_kernel(const float4* __restrict__ ue, const float4* __restrict__ ie,
                                const int* __restrict__ row_ptr, half4* __restrict__ xp,
                                int nu, int nn) {
    size_t i = (size_t)blockIdx.x * blockDim.x + threadIdx.x;
    if (i >= (size_t)nn * 16) return;
    int node = (int)(i >> 4);
    float4 v = (node < nu) ? ue[i] : ie[i - (size_t)nu * 16];
    int d = row_ptr[node + 1] - row_ptr[node];
    float dn = rsqrtf(1e-7f + (float)d);
    half4 h;
    h.x = (_Float16)(v.x * dn); h.y = (_Float16)(v.y * dn);
    h.z = (_Float16)(v.z * dn); h.w = (_Float16)(v.w * dn);
    xp[i] = h;
}

// ---------- fused gather-SpMM + cosine reweight + acc ----------
// one wave per node; 8 sub-groups of 8 lanes, each lane loads half8 (16 B,
// dwordx4) -> one gather instr serves a full 128-B row with 8 lanes.
// 16 edges per step with 4 VMEM instrs (2 colidx + 2 row gathers).
// Accumulation in packed fp16; fp32 after the cross-subgroup merge.
// EGO16: cosine operand is the fp16 prescaled x0 row (dinv cancels):
//   w = dot(x,x0) / (max(|x|,eps) * max(|x0|, eps*dn))
template<bool EGO16>
__global__ void spmm_fused(const int* __restrict__ row_ptr, const int* __restrict__ colidx,
                           const half8* __restrict__ xp, const half8* __restrict__ x0,
                           const float4* __restrict__ eu, const float4* __restrict__ ei,
                           half8* __restrict__ xn, float4* __restrict__ acc,
                           int nu, int nn, int first, int last) {
    int node = (blockIdx.x * blockDim.x + threadIdx.x) >> 6;
    int lane = threadIdx.x & 63;
    int sub  = lane >> 3;        // edge slot within step (0..7)
    int li   = lane & 7;         // 16-B chunk index within row
    if (node >= nn) return;
    int start = row_ptr[node];
    int deg   = row_ptr[node + 1] - start;

    half8 acc0 = {(_Float16)0, (_Float16)0, (_Float16)0, (_Float16)0,
                  (_Float16)0, (_Float16)0, (_Float16)0, (_Float16)0};
    half8 acc1 = acc0;
    const unsigned li16 = (unsigned)li << 4;
    int j = 0;
    // full 16-edge steps: 4 VMEM in flight (2 colidx dwords + 2 dwordx4 gathers)
    for (; j + 16 <= deg; j += 16) {
        int s0 = colidx[start + j + sub];
        int s1 = colidx[start + j + 8 + sub];
        half8 h0 = *(const half8*)((const char*)xp + (((unsigned)s0 << 7) + li16));
        half8 h1 = *(const half8*)((const char*)xp + (((unsigned)s1 << 7) + li16));
        acc0 += h0;
        acc1 += h1;
    }
    // single predicated 16-wide tail
    if (j < deg) {
        int j0 = j + sub, j1 = j + 8 + sub;
        int s0 = colidx[j0 < deg ? start + j0 : start];
        int s1 = colidx[j1 < deg ? start + j1 : start];
        if (j0 < deg) acc0 += *(const half8*)((const char*)xp + (((unsigned)s0 << 7) + li16));
        if (j1 < deg) acc1 += *(const half8*)((const char*)xp + (((unsigned)s1 << 7) + li16));
    }
    // merge partial sums across the 8 sub-groups (lane bits 3..5)
    acc0 += acc1;
#pragma unroll
    for (int m = 8; m <= 32; m <<= 1) {
        int4v p = __builtin_bit_cast(int4v, acc0);
        int4v q;
        q.x = __shfl_xor(p.x, m, 64);
        q.y = __shfl_xor(p.y, m, 64);
        q.z = __shfl_xor(p.z, m, 64);
        q.w = __shfl_xor(p.w, m, 64);
        acc0 += __builtin_bit_cast(half8, q);
    }
    float dn = rsqrtf(1e-7f + (float)deg);
    float xv[8];
#pragma unroll
    for (int k = 0; k < 8; k++) xv[k] = (float)acc0[k] * dn;

    float ev[8];
    if constexpr (EGO16) {
        half8 e = *(const half8*)((const char*)x0 + (((size_t)node << 7) + li16));
#pragma unroll
        for (int k = 0; k < 8; k++) ev[k] = (float)e[k];
    } else {
        size_t o32 = (size_t)node * 16 + 2 * li;
        float4 e0 = (node < nu) ? eu[o32] : ei[o32 - (size_t)nu * 16];
        float4 e1 = (node < nu) ? eu[o32 + 1] : ei[o32 + 1 - (size_t)nu * 16];
        ev[0] = e0.x; ev[1] = e0.y; ev[2] = e0.z; ev[3] = e0.w;
        ev[4] = e1.x; ev[5] = e1.y; ev[6] = e1.z; ev[7] = e1.w;
    }
    float dp = 0.f, np = 0.f, ep = 0.f;
#pragma unroll
    for (int k = 0; k < 8; k++) {
        dp += xv[k] * ev[k];
        np += xv[k] * xv[k];
        ep += ev[k] * ev[k];
    }
#pragma unroll
    for (int m = 1; m <= 4; m <<= 1) {
        dp += __shfl_xor(dp, m, 64);
        np += __shfl_xor(np, m, 64);
        ep += __shfl_xor(ep, m, 64);
    }
    float en = EGO16 ? fmaxf(sqrtf(ep), 1e-8f * dn) : fmaxf(sqrtf(ep), 1e-8f);
    float w = dp / (fmaxf(sqrtf(np), 1e-8f) * en);
    float yv[8];
#pragma unroll
    for (int k = 0; k < 8; k++) yv[k] = w * xv[k];

    if (sub == 0) {
        if (!last) {
            half8 h;
#pragma unroll
            for (int k = 0; k < 8; k++) h[k] = (_Float16)(yv[k] * dn);
            *(half8*)((char*)xn + (((size_t)node << 7) + li16)) = h;
        }
        size_t o = (size_t)node * 16 + 2 * li;
        float4 f0 = make_float4(yv[0], yv[1], yv[2], yv[3]);
        float4 f1 = make_float4(yv[4], yv[5], yv[6], yv[7]);
        if (first) {
            acc[o] = f0;
            acc[o + 1] = f1;
        } else {
            float4 t0 = acc[o], t1 = acc[o + 1];
            acc[o]     = make_float4(t0.x + f0.x, t0.y + f0.y, t0.z + f0.z, t0.w + f0.w);
            acc[o + 1] = make_float4(t1.x + f1.x, t1.y + f1.y, t1.z + f1.z, t1.w + f1.w);
        }
    }
}

extern "C" void kernel_launch(void* const* d_in, const int* in_sizes, int n_in,
                              void* d_out, int out_size, void* d_ws, size_t ws_size,
                              hipStream_t stream) {
    const float* uemb = (const float*)d_in[0];
    const float* iemb = (const float*)d_in[1];
    const int*   rows = (const int*)d_in[2];
    const int*   cols = (const int*)d_in[3];
    // d_in[4] = n_layers; fixed at 3 (identical work per call required)

    const int nu = in_sizes[0] / DIM;
    const int ni = in_sizes[1] / DIM;
    const int E  = in_sizes[2];
    const int nn = nu + ni;
    const int nb = (nn + SPAN - 1) >> NSHIFT;   // buckets (<= MAXNB for nn <= 524288)

    // ---- workspace layout ----
    const size_t hbuf = (size_t)nn * 16 * sizeof(half4);     // 128 B/node
    const size_t rec_bytes = (size_t)nb * BCAP * sizeof(int);
    const size_t bufB = hbuf > rec_bytes ? hbuf : rec_bytes;
    const size_t cid_bytes = (size_t)2 * E * sizeof(int);
    const size_t rp_bytes  = (size_t)(nn + 1) * sizeof(int);
    const size_t bc_bytes  = (size_t)MAXNB * 16 * sizeof(int);
    const size_t bb_bytes  = (size_t)MAXNB * sizeof(int);
    const size_t need3 = hbuf + bufB + hbuf + cid_bytes + rp_bytes + bc_bytes + bb_bytes + 1024;
    const bool ego16 = (ws_size >= need3);   // 3-buffer fp16-ego path if ws allows

    char* ws = (char*)d_ws;
    half4* A = (half4*)ws;                       // x0 = prescaled ego (fp16)
    half4* B = (half4*)(ws + hbuf);              // xn buffer 1 (aliases rec during build)
    half4* C = nullptr;
    char* after;
    if (ego16) { C = (half4*)(ws + hbuf + bufB); after = ws + hbuf + bufB + hbuf; }
    else       { after = ws + hbuf + bufB; }
    int* colidx   = (int*)after;
    int* row_ptr  = (int*)(after + cid_bytes);
    int* bkt_cnt  = (int*)(after + cid_bytes + rp_bytes);
    int* bkt_base = (int*)(after + cid_bytes + rp_bytes + bc_bytes);
    int* rec      = (int*)B;

    // ---- build normalized CSR: 3 kernels, zero random global atomics ----
    hipMemsetAsync(bkt_cnt, 0, bc_bytes, stream);
    bucket_scatter2<<<(E + EPB - 1) / EPB, 256, 0, stream>>>(rows, cols, bkt_cnt, rec, nu, nb, E);
    bucket_scan<<<1, 1024, 0, stream>>>(bkt_cnt, bkt_base, row_ptr + nn, nb);
    bucket_fill3<<<nb, 256, 0, stream>>>(bkt_cnt, bkt_base, rec, colidx, row_ptr, nn);

    // ---- prescale layer-0 input (full-grid; deg from row_ptr deltas) ----
    {
        size_t thr = (size_t)nn * 16;
        prescale_kernel<<<(unsigned)((thr + 255) / 256), 256, 0, stream>>>(
            (const float4*)uemb, (const float4*)iemb, row_ptr, A, nu, nn);
    }

    // ---- 3 fused SpMM+reweight layers (one wave per node, 16B/lane gathers) ----
    unsigned gs = (unsigned)(((size_t)nn * 64 + 255) / 256);
    float4* out = (float4*)d_out;
    if (ego16) {
        spmm_fused<true><<<gs, 256, 0, stream>>>(row_ptr, colidx, (const half8*)A, (const half8*)A,
                                                 nullptr, nullptr, (half8*)B, out, nu, nn, 1, 0);
        spmm_fused<true><<<gs, 256, 0, stream>>>(row_ptr, colidx, (const half8*)B, (const half8*)A,
                                                 nullptr, nullptr, (half8*)C, out, nu, nn, 0, 0);
        spmm_fused<true><<<gs, 256, 0, stream>>>(row_ptr, colidx, (const half8*)C, (const half8*)A,
                                                 nullptr, nullptr, nullptr, out, nu, nn, 0, 1);
    } else {
        spmm_fused<false><<<gs, 256, 0, stream>>>(row_ptr, colidx, (const half8*)A, nullptr,
                                                  (const float4*)uemb, (const float4*)iemb,
                                                  (half8*)B, out, nu, nn, 1, 0);
        spmm_fused<false><<<gs, 256, 0, stream>>>(row_ptr, colidx, (const half8*)B, nullptr,
                                                  (const float4*)uemb, (const float4*)iemb,
                                                  (half8*)A, out, nu, nn, 0, 0);
        spmm_fused<false><<<gs, 256, 0, stream>>>(row_ptr, colidx, (const half8*)A, nullptr,
                                                  (const float4*)uemb, (const float4*)iemb,
                                                  nullptr, out, nu, nn, 0, 1);
    }
}

// Round 6
// 529.392 us; speedup vs baseline: 1.8800x; 1.1765x over previous
//
#include <hip/hip_runtime.h>

#define DIM 64

// ---- bucket-scatter CSR build parameters ----
#define SPAN 256            // nodes per bucket
#define NSHIFT 8            // log2(SPAN)
#define MAXNB 2048          // max buckets (nn <= 524288)
#define BCAP 8192           // records per bucket region (item-bucket mean ~5120 + ~42 sigma)
#define EPT 16              // edges per thread in pass A
#define EPB (256 * EPT)     // edges per block in pass A (4096)

typedef __attribute__((ext_vector_type(4))) _Float16 half4;
typedef __attribute__((ext_vector_type(8))) _Float16 half8;

// ---------- CSR build, pass A: bucket the directed edge records ----------
// Record: (dst & 255) | (src << 8); src < 2^19 -> fits 27 bits.
// Bucket b's records go to rec[b*BCAP ..), counted in bucket_cnt[b*16].
__global__ void bucket_scatter2(const int* __restrict__ rows, const int* __restrict__ cols,
                                int* __restrict__ bucket_cnt, int* __restrict__ rec,
                                int nu, int nb, int E) {
    __shared__ int hist[MAXNB];
    __shared__ int base[MAXNB];
    int t = threadIdx.x;
    for (int b = t; b < MAXNB; b += 256) hist[b] = 0;
    __syncthreads();
    int e0 = blockIdx.x * EPB;
    int e1 = min(e0 + EPB, E);
    for (int e = e0 + t; e < e1; e += 256) {
        int r = rows[e];
        int c = nu + cols[e];
        atomicAdd(&hist[r >> NSHIFT], 1);
        atomicAdd(&hist[c >> NSHIFT], 1);
    }
    __syncthreads();
    for (int b = t; b < nb; b += 256) {
        int h = hist[b];
        int off = 0;
        if (h) off = atomicAdd(&bucket_cnt[b * 16], h);
        if (off > BCAP) off = BCAP;  // memory-safety clamp (statistically unreachable)
        base[b] = b * BCAP + off;
        hist[b] = 0;  // reuse as within-chunk running offset
    }
    __syncthreads();
    for (int e = e0 + t; e < e1; e += 256) {
        int r = rows[e];
        int c = nu + cols[e];
        int b1 = r >> NSHIFT;
        int p1 = atomicAdd(&hist[b1], 1);
        rec[base[b1] + p1] = (r & (SPAN - 1)) | (c << NSHIFT);
        int b2 = c >> NSHIFT;
        int p2 = atomicAdd(&hist[b2], 1);
        rec[base[b2] + p2] = (c & (SPAN - 1)) | (r << NSHIFT);
    }
}

// ---------- CSR build, pass B: per-bucket scan + deg histogram + place + prescale ----------
// One block per bucket (256 nodes, 1 node/thread for the scans).
// The global bucket-base prefix is recomputed redundantly per block from the
// (L2-hot) padded bucket counters -- removes the single-block scan kernel.
// After placement, LDS counters hold each node's degree, so the fused
// prescale epilogue writes x0 = dinv * ego (fp16) with zero extra passes.
__global__ void bucket_fill3(const int* __restrict__ bucket_cnt, const int* __restrict__ rec,
                             int* __restrict__ colidx, int* __restrict__ row_ptr,
                             const float4* __restrict__ ue, const float4* __restrict__ ie,
                             half4* __restrict__ x0, int nu, int nn, int nb) {
    __shared__ int cnt[SPAN];   // histogram -> per-node start offset
    __shared__ int lds[256];    // scan buffer -> placement counters -> degrees
    int t = threadIdx.x;
    int b = blockIdx.x;
    // inline scan: gbase = sum of bucket counts before b
    int gbase;
    {
        int part = 0;
        for (int i = t; i < b; i += 256) part += bucket_cnt[i * 16];
        lds[t] = part; __syncthreads();
        for (int off = 128; off >= 1; off >>= 1) {
            if (t < off) lds[t] += lds[t + off];
            __syncthreads();
        }
        gbase = lds[0];
        __syncthreads();
    }
    int nrec = bucket_cnt[b * 16];
    const int* r0 = rec + (size_t)b * BCAP;

    // degree histogram
    cnt[t] = 0;
    __syncthreads();
    for (int i = t; i < nrec; i += 256)
        atomicAdd(&cnt[r0[i] & (SPAN - 1)], 1);
    __syncthreads();
    // 256-wide exclusive scan (1 node/thread)
    int d = cnt[t];
    lds[t] = d; __syncthreads();
    for (int off = 1; off < 256; off <<= 1) {
        int add = (t >= off) ? lds[t - off] : 0;
        __syncthreads();
        lds[t] += add;
        __syncthreads();
    }
    int excl = lds[t] - d;
    int node = (b << NSHIFT) + t;
    if (node < nn) row_ptr[node] = gbase + excl;
    if (b == nb - 1 && t == 0) row_ptr[nn] = gbase + nrec;
    cnt[t] = excl;   // per-node start offset
    lds[t] = 0;      // placement counters
    __syncthreads();
    // place records
    for (int i = t; i < nrec; i += 256) {
        int v = r0[i];
        int dl = v & (SPAN - 1);
        int pos = gbase + cnt[dl] + atomicAdd(&lds[dl], 1);
        colidx[pos] = v >> NSHIFT;
    }
    __syncthreads();
    // fused prescale: lds[nl] == degree of node nl; x0 = dinv * ego (fp16)
    for (int i = t; i < SPAN * 16; i += 256) {
        int nl = i >> 4;
        int node2 = (b << NSHIFT) + nl;
        if (node2 >= nn) break;    // node2 monotone in i -> safe
        int li = i & 15;
        float dn = rsqrtf(1e-7f + (float)lds[nl]);
        size_t o = (size_t)node2 * 16 + li;
        float4 v = (node2 < nu) ? ue[o] : ie[o - (size_t)nu * 16];
        half4 h;
        h.x = (_Float16)(v.x * dn); h.y = (_Float16)(v.y * dn);
        h.z = (_Float16)(v.z * dn); h.w = (_Float16)(v.w * dn);
        x0[o] = h;
    }
}

// ---------- fused gather-SpMM + cosine reweight + acc ----------
// 8 lanes per node, 8 nodes per wave: each lane owns one 16-B chunk of its
// node's row, so there is NO cross-subgroup merge; the epilogue (dots, norms,
// w, stores) is amortized over 8 nodes per wave.  Inner loop: 4 edges/iter,
// 4 independent packed-fp16 accumulator chains, 8 VMEM instrs per 32 edges
// per wave.  Loop runs to max-deg of the 8 resident nodes (mean deg ~13).
// EGO16: cosine operand is the fp16 prescaled x0 row (dinv cancels):
//   w = dot(x,x0) / (max(|x|,eps) * max(|x0|, eps*dn))
template<bool EGO16>
__global__ void spmm_fused(const int* __restrict__ row_ptr, const int* __restrict__ colidx,
                           const half8* __restrict__ xp, const half8* __restrict__ x0,
                           const float4* __restrict__ eu, const float4* __restrict__ ei,
                           half8* __restrict__ xn, float4* __restrict__ acc,
                           int nu, int nn, int first, int last) {
    int gid  = (int)(blockIdx.x * blockDim.x + threadIdx.x) >> 3;  // node index
    int li   = threadIdx.x & 7;                                    // 16-B chunk in row
    bool valid = gid < nn;
    int node = valid ? gid : nn - 1;
    int start = row_ptr[node];
    int deg   = row_ptr[node + 1] - start;

    const half8 hz = {(_Float16)0, (_Float16)0, (_Float16)0, (_Float16)0,
                      (_Float16)0, (_Float16)0, (_Float16)0, (_Float16)0};
    half8 a0 = hz, a1 = hz, a2 = hz, a3 = hz;
    const unsigned li16 = (unsigned)li << 4;
    const char* xpb = (const char*)xp;
    int j = 0;
    for (; j + 4 <= deg; j += 4) {
        int s0 = colidx[start + j];
        int s1 = colidx[start + j + 1];
        int s2 = colidx[start + j + 2];
        int s3 = colidx[start + j + 3];
        a0 += *(const half8*)(xpb + (((unsigned)s0 << 7) + li16));
        a1 += *(const half8*)(xpb + (((unsigned)s1 << 7) + li16));
        a2 += *(const half8*)(xpb + (((unsigned)s2 << 7) + li16));
        a3 += *(const half8*)(xpb + (((unsigned)s3 << 7) + li16));
    }
    if (j < deg) {
        int laste = start + deg - 1;
        int s0 = colidx[start + j];
        int s1 = colidx[min(start + j + 1, laste)];
        int s2 = colidx[min(start + j + 2, laste)];
        a0 += *(const half8*)(xpb + (((unsigned)s0 << 7) + li16));
        if (j + 1 < deg) a1 += *(const half8*)(xpb + (((unsigned)s1 << 7) + li16));
        if (j + 2 < deg) a2 += *(const half8*)(xpb + (((unsigned)s2 << 7) + li16));
    }
    a0 += a1; a2 += a3; a0 += a2;

    float dn = rsqrtf(1e-7f + (float)deg);
    float xv[8];
#pragma unroll
    for (int k = 0; k < 8; k++) xv[k] = (float)a0[k] * dn;

    float ev[8];
    if constexpr (EGO16) {
        half8 e = *(const half8*)((const char*)x0 + (((size_t)node << 7) + li16));
#pragma unroll
        for (int k = 0; k < 8; k++) ev[k] = (float)e[k];
    } else {
        size_t o32 = (size_t)node * 16 + 2 * li;
        float4 e0 = (node < nu) ? eu[o32] : ei[o32 - (size_t)nu * 16];
        float4 e1 = (node < nu) ? eu[o32 + 1] : ei[o32 + 1 - (size_t)nu * 16];
        ev[0] = e0.x; ev[1] = e0.y; ev[2] = e0.z; ev[3] = e0.w;
        ev[4] = e1.x; ev[5] = e1.y; ev[6] = e1.z; ev[7] = e1.w;
    }
    float dp = 0.f, np = 0.f, ep = 0.f;
#pragma unroll
    for (int k = 0; k < 8; k++) {
        dp += xv[k] * ev[k];
        np += xv[k] * xv[k];
        ep += ev[k] * ev[k];
    }
    // reduce within the 8-lane group (masks stay inside the group)
#pragma unroll
    for (int m = 1; m <= 4; m <<= 1) {
        dp += __shfl_xor(dp, m, 64);
        np += __shfl_xor(np, m, 64);
        ep += __shfl_xor(ep, m, 64);
    }
    float en = EGO16 ? fmaxf(sqrtf(ep), 1e-8f * dn) : fmaxf(sqrtf(ep), 1e-8f);
    float w = dp / (fmaxf(sqrtf(np), 1e-8f) * en);

    if (valid) {
        if (!last) {
            half8 h;
#pragma unroll
            for (int k = 0; k < 8; k++) h[k] = (_Float16)(w * xv[k] * dn);
            *(half8*)((char*)xn + (((size_t)node << 7) + li16)) = h;
        }
        size_t o = (size_t)node * 16 + 2 * li;
        float4 f0 = make_float4(w * xv[0], w * xv[1], w * xv[2], w * xv[3]);
        float4 f1 = make_float4(w * xv[4], w * xv[5], w * xv[6], w * xv[7]);
        if (first) {
            acc[o] = f0;
            acc[o + 1] = f1;
        } else {
            float4 t0 = acc[o], t1 = acc[o + 1];
            acc[o]     = make_float4(t0.x + f0.x, t0.y + f0.y, t0.z + f0.z, t0.w + f0.w);
            acc[o + 1] = make_float4(t1.x + f1.x, t1.y + f1.y, t1.z + f1.z, t1.w + f1.w);
        }
    }
}

extern "C" void kernel_launch(void* const* d_in, const int* in_sizes, int n_in,
                              void* d_out, int out_size, void* d_ws, size_t ws_size,
                              hipStream_t stream) {
    const float* uemb = (const float*)d_in[0];
    const float* iemb = (const float*)d_in[1];
    const int*   rows = (const int*)d_in[2];
    const int*   cols = (const int*)d_in[3];
    // d_in[4] = n_layers; fixed at 3 (identical work per call required)

    const int nu = in_sizes[0] / DIM;
    const int ni = in_sizes[1] / DIM;
    const int E  = in_sizes[2];
    const int nn = nu + ni;
    const int nb = (nn + SPAN - 1) >> NSHIFT;   // buckets (<= MAXNB for nn <= 524288)

    // ---- workspace layout ----
    const size_t hbuf = (size_t)nn * 16 * sizeof(half4);     // 128 B/node
    const size_t rec_bytes = (size_t)nb * BCAP * sizeof(int);
    const size_t bufB = hbuf > rec_bytes ? hbuf : rec_bytes;
    const size_t cid_bytes = (size_t)2 * E * sizeof(int);
    const size_t rp_bytes  = (size_t)(nn + 1) * sizeof(int);
    const size_t bc_bytes  = (size_t)MAXNB * 16 * sizeof(int);
    const size_t need3 = hbuf + bufB + hbuf + cid_bytes + rp_bytes + bc_bytes + 1024;
    const bool ego16 = (ws_size >= need3);   // 3-buffer fp16-ego path if ws allows

    char* ws = (char*)d_ws;
    half4* A = (half4*)ws;                       // x0 = prescaled ego (fp16)
    half4* B = (half4*)(ws + hbuf);              // xn buffer 1 (aliases rec during build)
    half4* C = nullptr;
    char* after;
    if (ego16) { C = (half4*)(ws + hbuf + bufB); after = ws + hbuf + bufB + hbuf; }
    else       { after = ws + hbuf + bufB; }
    int* colidx   = (int*)after;
    int* row_ptr  = (int*)(after + cid_bytes);
    int* bkt_cnt  = (int*)(after + cid_bytes + rp_bytes);
    int* rec      = (int*)B;

    // ---- build normalized CSR + prescale: 2 kernels, zero random global atomics ----
    hipMemsetAsync(bkt_cnt, 0, bc_bytes, stream);
    bucket_scatter2<<<(E + EPB - 1) / EPB, 256, 0, stream>>>(rows, cols, bkt_cnt, rec, nu, nb, E);
    bucket_fill3<<<nb, 256, 0, stream>>>(bkt_cnt, rec, colidx, row_ptr,
                                         (const float4*)uemb, (const float4*)iemb, A, nu, nn, nb);

    // ---- 3 fused SpMM+reweight layers (8 lanes/node, 8 nodes/wave) ----
    unsigned gs = (unsigned)(((size_t)nn * 8 + 255) / 256);
    float4* out = (float4*)d_out;
    if (ego16) {
        spmm_fused<true><<<gs, 256, 0, stream>>>(row_ptr, colidx, (const half8*)A, (const half8*)A,
                                                 nullptr, nullptr, (half8*)B, out, nu, nn, 1, 0);
        spmm_fused<true><<<gs, 256, 0, stream>>>(row_ptr, colidx, (const half8*)B, (const half8*)A,
                                                 nullptr, nullptr, (half8*)C, out, nu, nn, 0, 0);
        spmm_fused<true><<<gs, 256, 0, stream>>>(row_ptr, colidx, (const half8*)C, (const half8*)A,
                                                 nullptr, nullptr, nullptr, out, nu, nn, 0, 1);
    } else {
        spmm_fused<false><<<gs, 256, 0, stream>>>(row_ptr, colidx, (const half8*)A, nullptr,
                                                  (const float4*)uemb, (const float4*)iemb,
                                                  (half8*)B, out, nu, nn, 1, 0);
        spmm_fused<false><<<gs, 256, 0, stream>>>(row_ptr, colidx, (const half8*)B, nullptr,
                                                  (const float4*)uemb, (const float4*)iemb,
                                                  (half8*)A, out, nu, nn, 0, 0);
        spmm_fused<false><<<gs, 256, 0, stream>>>(row_ptr, colidx, (const half8*)A, nullptr,
                                                  (const float4*)uemb, (const float4*)iemb,
                                                  nullptr, out, nu, nn, 0, 1);
    }
}

// Round 7
// 507.528 us; speedup vs baseline: 1.9609x; 1.0431x over previous
//
#include <hip/hip_runtime.h>

#define DIM 64

// ---- bucket-scatter CSR build parameters ----
#define SPAN 256            // nodes per bucket
#define NSHIFT 8            // log2(SPAN)
#define MAXNB 2048          // max buckets (nn <= 524288)
#define BCAP 8192           // records per bucket region (item-bucket mean ~5120 + ~42 sigma)
#define EPT 32              // edges per thread in pass A
#define EPB (256 * EPT)     // edges per block in pass A (8192)

typedef __attribute__((ext_vector_type(4))) _Float16 half4;
typedef __attribute__((ext_vector_type(8))) _Float16 half8;

// ---------- CSR build, pass A: bucket the directed edge records ----------
// Record: (dst & 255) | (src << 8); src < 2^19 -> fits 27 bits.
// Bucket b's records go to rec[b*BCAP ..), counted in bucket_cnt[b*16]
// (64B-padded counters).  Per-block LDS histogram => ~1 global atomic per
// bucket per block + chunk-wise appends (~56 B/bucket/block at EPT=32).
__global__ void bucket_scatter2(const int* __restrict__ rows, const int* __restrict__ cols,
                                int* __restrict__ bucket_cnt, int* __restrict__ rec,
                                int nu, int nb, int E) {
    __shared__ int hist[MAXNB];
    __shared__ int base[MAXNB];
    int t = threadIdx.x;
    for (int b = t; b < MAXNB; b += 256) hist[b] = 0;
    __syncthreads();
    int e0 = blockIdx.x * EPB;
    int e1 = min(e0 + EPB, E);
    for (int e = e0 + t; e < e1; e += 256) {
        int r = rows[e];
        int c = nu + cols[e];
        atomicAdd(&hist[r >> NSHIFT], 1);
        atomicAdd(&hist[c >> NSHIFT], 1);
    }
    __syncthreads();
    for (int b = t; b < nb; b += 256) {
        int h = hist[b];
        int off = 0;
        if (h) off = atomicAdd(&bucket_cnt[b * 16], h);
        if (off > BCAP) off = BCAP;  // memory-safety clamp (statistically unreachable)
        base[b] = b * BCAP + off;
        hist[b] = 0;  // reuse as within-chunk running offset
    }
    __syncthreads();
    for (int e = e0 + t; e < e1; e += 256) {
        int r = rows[e];
        int c = nu + cols[e];
        int b1 = r >> NSHIFT;
        int p1 = atomicAdd(&hist[b1], 1);
        rec[base[b1] + p1] = (r & (SPAN - 1)) | (c << NSHIFT);
        int b2 = c >> NSHIFT;
        int p2 = atomicAdd(&hist[b2], 1);
        rec[base[b2] + p2] = (c & (SPAN - 1)) | (r << NSHIFT);
    }
}

// ---------- CSR build, pass B: scan bucket sizes -> global bases ----------
// 1024 threads x 2 elements covers nb <= 2048.
__global__ void bucket_scan(const int* __restrict__ bucket_cnt, int* __restrict__ bucket_base,
                            int* __restrict__ row_ptr_end, int nb) {
    __shared__ int lds[1024];
    int t = threadIdx.x;
    int i0 = 2 * t, i1 = 2 * t + 1;
    int v0 = (i0 < nb) ? bucket_cnt[i0 * 16] : 0;
    int v1 = (i1 < nb) ? bucket_cnt[i1 * 16] : 0;
    int s = v0 + v1;
    lds[t] = s; __syncthreads();
    for (int off = 1; off < 1024; off <<= 1) {
        int add = (t >= off) ? lds[t - off] : 0;
        __syncthreads();
        lds[t] += add;
        __syncthreads();
    }
    int excl = lds[t] - s;
    if (i0 < nb) bucket_base[i0] = excl;
    if (i1 < nb) bucket_base[i1] = excl + v0;
    if (i0 == nb - 1) *row_ptr_end = excl + v0;
    if (i1 == nb - 1) *row_ptr_end = excl + v0 + v1;
}

// ---------- CSR build, pass C: per-bucket deg histogram + scan + place ----------
// One block per bucket (256 nodes = 256 threads, 1 node/thread for the scan).
__global__ void bucket_fill3(const int* __restrict__ bucket_cnt, const int* __restrict__ bucket_base,
                             const int* __restrict__ rec, int* __restrict__ colidx,
                             int* __restrict__ row_ptr, int nn) {
    __shared__ int cnt[SPAN];   // histogram -> per-node start offset
    __shared__ int lds[256];    // scan buffer -> placement counters
    int t = threadIdx.x;
    int b = blockIdx.x;
    int nrec = bucket_cnt[b * 16];
    const int* r0 = rec + (size_t)b * BCAP;
    int gbase = bucket_base[b];

    cnt[t] = 0;
    __syncthreads();
    for (int i = t; i < nrec; i += 256)
        atomicAdd(&cnt[r0[i] & (SPAN - 1)], 1);
    __syncthreads();
    int d = cnt[t];
    lds[t] = d; __syncthreads();
    for (int off = 1; off < 256; off <<= 1) {
        int add = (t >= off) ? lds[t - off] : 0;
        __syncthreads();
        lds[t] += add;
        __syncthreads();
    }
    int excl = lds[t] - d;
    int node = (b << NSHIFT) + t;
    if (node < nn) row_ptr[node] = gbase + excl;
    cnt[t] = excl;   // per-node start offset
    lds[t] = 0;      // placement counters
    __syncthreads();
    for (int i = t; i < nrec; i += 256) {
        int v = r0[i];
        int dl = v & (SPAN - 1);
        int pos = gbase + cnt[dl] + atomicAdd(&lds[dl], 1);
        colidx[pos] = v >> NSHIFT;
    }
}

// ---------- pre-scale: x0 = dinv ⊙ ego (fp16); deg from row_ptr deltas ----------
__global__ void prescale_kernel(const float4* __restrict__ ue, const float4* __restrict__ ie,
                                const int* __restrict__ row_ptr, half4* __restrict__ xp,
                                int nu, int nn) {
    size_t i = (size_t)blockIdx.x * blockDim.x + threadIdx.x;
    if (i >= (size_t)nn * 16) return;
    int node = (int)(i >> 4);
    float4 v = (node < nu) ? ue[i] : ie[i - (size_t)nu * 16];
    int d = row_ptr[node + 1] - row_ptr[node];
    float dn = rsqrtf(1e-7f + (float)d);
    half4 h;
    h.x = (_Float16)(v.x * dn); h.y = (_Float16)(v.y * dn);
    h.z = (_Float16)(v.z * dn); h.w = (_Float16)(v.w * dn);
    xp[i] = h;
}

// ---------- fused gather-SpMM + cosine reweight + acc ----------
// 8 lanes per node, 8 nodes per wave: each lane owns one 16-B chunk of its
// node's row, so there is NO cross-subgroup merge; the epilogue (dots, norms,
// w, stores) is amortized over 8 nodes per wave.  Inner loop: 4 edges/iter,
// 4 independent packed-fp16 accumulator chains.
// EGO16: cosine operand is the fp16 prescaled x0 row (dinv cancels):
//   w = dot(x,x0) / (max(|x|,eps) * max(|x0|, eps*dn))
template<bool EGO16>
__global__ void spmm_fused(const int* __restrict__ row_ptr, const int* __restrict__ colidx,
                           const half8* __restrict__ xp, const half8* __restrict__ x0,
                           const float4* __restrict__ eu, const float4* __restrict__ ei,
                           half8* __restrict__ xn, float4* __restrict__ acc,
                           int nu, int nn, int first, int last) {
    int gid  = (int)(blockIdx.x * blockDim.x + threadIdx.x) >> 3;  // node index
    int li   = threadIdx.x & 7;                                    // 16-B chunk in row
    bool valid = gid < nn;
    int node = valid ? gid : nn - 1;
    int start = row_ptr[node];
    int deg   = row_ptr[node + 1] - start;

    const half8 hz = {(_Float16)0, (_Float16)0, (_Float16)0, (_Float16)0,
                      (_Float16)0, (_Float16)0, (_Float16)0, (_Float16)0};
    half8 a0 = hz, a1 = hz, a2 = hz, a3 = hz;
    const unsigned li16 = (unsigned)li << 4;
    const char* xpb = (const char*)xp;
    int j = 0;
    for (; j + 4 <= deg; j += 4) {
        int s0 = colidx[start + j];
        int s1 = colidx[start + j + 1];
        int s2 = colidx[start + j + 2];
        int s3 = colidx[start + j + 3];
        a0 += *(const half8*)(xpb + (((unsigned)s0 << 7) + li16));
        a1 += *(const half8*)(xpb + (((unsigned)s1 << 7) + li16));
        a2 += *(const half8*)(xpb + (((unsigned)s2 << 7) + li16));
        a3 += *(const half8*)(xpb + (((unsigned)s3 << 7) + li16));
    }
    if (j < deg) {
        int laste = start + deg - 1;
        int s0 = colidx[start + j];
        int s1 = colidx[min(start + j + 1, laste)];
        int s2 = colidx[min(start + j + 2, laste)];
        a0 += *(const half8*)(xpb + (((unsigned)s0 << 7) + li16));
        if (j + 1 < deg) a1 += *(const half8*)(xpb + (((unsigned)s1 << 7) + li16));
        if (j + 2 < deg) a2 += *(const half8*)(xpb + (((unsigned)s2 << 7) + li16));
    }
    a0 += a1; a2 += a3; a0 += a2;

    float dn = rsqrtf(1e-7f + (float)deg);
    float xv[8];
#pragma unroll
    for (int k = 0; k < 8; k++) xv[k] = (float)a0[k] * dn;

    float ev[8];
    if constexpr (EGO16) {
        half8 e = *(const half8*)((const char*)x0 + (((size_t)node << 7) + li16));
#pragma unroll
        for (int k = 0; k < 8; k++) ev[k] = (float)e[k];
    } else {
        size_t o32 = (size_t)node * 16 + 2 * li;
        float4 e0 = (node < nu) ? eu[o32] : ei[o32 - (size_t)nu * 16];
        float4 e1 = (node < nu) ? eu[o32 + 1] : ei[o32 + 1 - (size_t)nu * 16];
        ev[0] = e0.x; ev[1] = e0.y; ev[2] = e0.z; ev[3] = e0.w;
        ev[4] = e1.x; ev[5] = e1.y; ev[6] = e1.z; ev[7] = e1.w;
    }
    float dp = 0.f, np = 0.f, ep = 0.f;
#pragma unroll
    for (int k = 0; k < 8; k++) {
        dp += xv[k] * ev[k];
        np += xv[k] * xv[k];
        ep += ev[k] * ev[k];
    }
    // reduce within the 8-lane group (masks stay inside the group)
#pragma unroll
    for (int m = 1; m <= 4; m <<= 1) {
        dp += __shfl_xor(dp, m, 64);
        np += __shfl_xor(np, m, 64);
        ep += __shfl_xor(ep, m, 64);
    }
    float en = EGO16 ? fmaxf(sqrtf(ep), 1e-8f * dn) : fmaxf(sqrtf(ep), 1e-8f);
    float w = dp / (fmaxf(sqrtf(np), 1e-8f) * en);

    if (valid) {
        if (!last) {
            half8 h;
#pragma unroll
            for (int k = 0; k < 8; k++) h[k] = (_Float16)(w * xv[k] * dn);
            *(half8*)((char*)xn + (((size_t)node << 7) + li16)) = h;
        }
        size_t o = (size_t)node * 16 + 2 * li;
        float4 f0 = make_float4(w * xv[0], w * xv[1], w * xv[2], w * xv[3]);
        float4 f1 = make_float4(w * xv[4], w * xv[5], w * xv[6], w * xv[7]);
        if (first) {
            acc[o] = f0;
            acc[o + 1] = f1;
        } else {
            float4 t0 = acc[o], t1 = acc[o + 1];
            acc[o]     = make_float4(t0.x + f0.x, t0.y + f0.y, t0.z + f0.z, t0.w + f0.w);
            acc[o + 1] = make_float4(t1.x + f1.x, t1.y + f1.y, t1.z + f1.z, t1.w + f1.w);
        }
    }
}

extern "C" void kernel_launch(void* const* d_in, const int* in_sizes, int n_in,
                              void* d_out, int out_size, void* d_ws, size_t ws_size,
                              hipStream_t stream) {
    const float* uemb = (const float*)d_in[0];
    const float* iemb = (const float*)d_in[1];
    const int*   rows = (const int*)d_in[2];
    const int*   cols = (const int*)d_in[3];
    // d_in[4] = n_layers; fixed at 3 (identical work per call required)

    const int nu = in_sizes[0] / DIM;
    const int ni = in_sizes[1] / DIM;
    const int E  = in_sizes[2];
    const int nn = nu + ni;
    const int nb = (nn + SPAN - 1) >> NSHIFT;   // buckets (<= MAXNB for nn <= 524288)

    // ---- workspace layout ----
    const size_t hbuf = (size_t)nn * 16 * sizeof(half4);     // 128 B/node
    const size_t rec_bytes = (size_t)nb * BCAP * sizeof(int);
    const size_t bufB = hbuf > rec_bytes ? hbuf : rec_bytes;
    const size_t cid_bytes = (size_t)2 * E * sizeof(int);
    const size_t rp_bytes  = (size_t)(nn + 1) * sizeof(int);
    const size_t bc_bytes  = (size_t)MAXNB * 16 * sizeof(int);
    const size_t bb_bytes  = (size_t)MAXNB * sizeof(int);
    const size_t need3 = hbuf + bufB + hbuf + cid_bytes + rp_bytes + bc_bytes + bb_bytes + 1024;
    const bool ego16 = (ws_size >= need3);   // 3-buffer fp16-ego path if ws allows

    char* ws = (char*)d_ws;
    half4* A = (half4*)ws;                       // x0 = prescaled ego (fp16)
    half4* B = (half4*)(ws + hbuf);              // xn buffer 1 (aliases rec during build)
    half4* C = nullptr;
    char* after;
    if (ego16) { C = (half4*)(ws + hbuf + bufB); after = ws + hbuf + bufB + hbuf; }
    else       { after = ws + hbuf + bufB; }
    int* colidx   = (int*)after;
    int* row_ptr  = (int*)(after + cid_bytes);
    int* bkt_cnt  = (int*)(after + cid_bytes + rp_bytes);
    int* bkt_base = (int*)(after + cid_bytes + rp_bytes + bc_bytes);
    int* rec      = (int*)B;

    // ---- build normalized CSR: 3 kernels, zero random global atomics ----
    hipMemsetAsync(bkt_cnt, 0, bc_bytes, stream);
    bucket_scatter2<<<(E + EPB - 1) / EPB, 256, 0, stream>>>(rows, cols, bkt_cnt, rec, nu, nb, E);
    bucket_scan<<<1, 1024, 0, stream>>>(bkt_cnt, bkt_base, row_ptr + nn, nb);
    bucket_fill3<<<nb, 256, 0, stream>>>(bkt_cnt, bkt_base, rec, colidx, row_ptr, nn);

    // ---- prescale layer-0 input (full-grid; deg from row_ptr deltas) ----
    {
        size_t thr = (size_t)nn * 16;
        prescale_kernel<<<(unsigned)((thr + 255) / 256), 256, 0, stream>>>(
            (const float4*)uemb, (const float4*)iemb, row_ptr, A, nu, nn);
    }

    // ---- 3 fused SpMM+reweight layers (8 lanes/node, 8 nodes/wave) ----
    unsigned gs = (unsigned)(((size_t)nn * 8 + 255) / 256);
    float4* out = (float4*)d_out;
    if (ego16) {
        spmm_fused<true><<<gs, 256, 0, stream>>>(row_ptr, colidx, (const half8*)A, (const half8*)A,
                                                 nullptr, nullptr, (half8*)B, out, nu, nn, 1, 0);
        spmm_fused<true><<<gs, 256, 0, stream>>>(row_ptr, colidx, (const half8*)B, (const half8*)A,
                                                 nullptr, nullptr, (half8*)C, out, nu, nn, 0, 0);
        spmm_fused<true><<<gs, 256, 0, stream>>>(row_ptr, colidx, (const half8*)C, (const half8*)A,
                                                 nullptr, nullptr, nullptr, out, nu, nn, 0, 1);
    } else {
        spmm_fused<false><<<gs, 256, 0, stream>>>(row_ptr, colidx, (const half8*)A, nullptr,
                                                  (const float4*)uemb, (const float4*)iemb,
                                                  (half8*)B, out, nu, nn, 1, 0);
        spmm_fused<false><<<gs, 256, 0, stream>>>(row_ptr, colidx, (const half8*)B, nullptr,
                                                  (const float4*)uemb, (const float4*)iemb,
                                                  (half8*)A, out, nu, nn, 0, 0);
        spmm_fused<false><<<gs, 256, 0, stream>>>(row_ptr, colidx, (const half8*)A, nullptr,
                                                  (const float4*)uemb, (const float4*)iemb,
                                                  nullptr, out, nu, nn, 0, 1);
    }
}